// Round 1
// baseline (453.828 us; speedup 1.0000x reference)
//
#include <hip/hip_runtime.h>

// Correlation cost volume, MAX_DISP=4 (81 displacements).
// out[b,(dy+4)*9+(dx+4),y,x] = (1/C) * sum_c first[b,c,y,x]*second[b,c,y+dy,x+dx]
//
// R8: OCCUPANCY DOUBLING. R7 counters: VALUBusy 24.7%, HBM 22%, Occupancy 22.7%
// -> latency-bound with a grid-limited wave supply (3456 waves = 3.375/SIMD).
// Per-wave issue ~100cyc/step vs ~2250cyc wall/step: waves are >90% stalled and
// there aren't enough of them to overlap. Fix: 2 px/thread (was 4) -> 6912 waves
// = 6.75/SIMD. Window is 10 floats [X-4, X+6) loaded as 5x float2 (+ float2
// first): float2 chunks at even X are always fully-valid or fully-in-pad
// (W=192 even), so zero-pad masking stays exact with no misaligned/OOB float4.
// Adjacent lanes overlap 8/10 window floats -> extra requests are L1 hits.
// Depth-4 named-register pipeline, ZERO barriers (R7-proven). acc = 9 float2.
// Grid 3x32x36 = 3456 blocks x 128 thr.

#define B_    4
#define C_    128
#define H_    128
#define W_    192
#define HW_   (H_ * W_)
#define CHW_  (C_ * HW_)

#define TX    64    // tile width (pixels) = 32 lanes * 2 px
#define TY    4     // tile height

__global__ __launch_bounds__(128, 6)
void corr_kernel(const float* __restrict__ first,
                 const float* __restrict__ second,
                 float* __restrict__ out)
{
    const int t  = threadIdx.x;
    const int tx = t & 31;       // 0..31 (2 px each)
    const int ty = t >> 5;       // 0..3
    const int x0 = blockIdx.x * TX;
    const int y0 = blockIdx.y * TY;
    const int bz = blockIdx.z;   // b*9 + (dy+4)
    const int b  = bz / 9;
    const int dyi = bz - 9 * b;  // 0..8
    const int dy  = dyi - 4;

    const int X = x0 + 2 * tx;   // this thread's first output x (even)
    const int y = y0 + ty;
    const int ys = y + dy;       // source row in second

    const float* fptr = first  + (size_t)b * CHW_ + (size_t)y  * W_ + X;
    // window base: second[b, c, ys, X-4] (guarded; only deref'd when valid)
    const float* wptr = second + (size_t)b * CHW_ + (size_t)ys * W_ + (X - 4);

    const bool rowv = (ys >= 0) && (ys < H_);
    // chunk j covers columns [X-4+2j, X-2+2j); fully valid or fully pad:
    const bool v0 = rowv && (X >= 4);     // [X-4, X-2)
    const bool v1 = rowv && (X >= 2);     // [X-2, X)
    const bool v2 = rowv;                 // [X,   X+2)  always in-range
    const bool v3 = rowv && (X <= 188);   // [X+2, X+4)
    const bool v4 = rowv && (X <= 186);   // [X+4, X+6)

    const float2 z2 = make_float2(0.f, 0.f);

    // named pipeline slots: slot K holds channel cb+K's window + first frag
    float2 A0,A1,A2,A3,A4,AF, B0,B1,B2,B3,B4,BF,
           C0,C1,C2,C3,C4,CF, D0,D1,D2,D3,D4,DF;

#define LOADSLOT(S0,S1,S2,S3,S4,SF,CN)                                  \
    {                                                                   \
        const size_t co = (size_t)(CN) * HW_;                           \
        S0 = v0 ? *(const float2*)(wptr + co + 0) : z2;                 \
        S1 = v1 ? *(const float2*)(wptr + co + 2) : z2;                 \
        S2 = v2 ? *(const float2*)(wptr + co + 4) : z2;                 \
        S3 = v3 ? *(const float2*)(wptr + co + 6) : z2;                 \
        S4 = v4 ? *(const float2*)(wptr + co + 8) : z2;                 \
        SF = *(const float2*)(fptr + co);                               \
    }

    // prologue: load channels 0..3
    LOADSLOT(A0,A1,A2,A3,A4,AF, 0)
    LOADSLOT(B0,B1,B2,B3,B4,BF, 1)
    LOADSLOT(C0,C1,C2,C3,C4,CF, 2)
    LOADSLOT(D0,D1,D2,D3,D4,DF, 3)

    float2 acc[9];
    #pragma unroll
    for (int i = 0; i < 9; ++i) acc[i] = z2;

// one step: snapshot slot (w[10] is SROA'd to pure register renames), issue
// channel CN's loads into the slot (they fly for ~3 more steps), then FMA.
#define STEP(S0,S1,S2,S3,S4,SF,CN)                                      \
    {                                                                   \
        float w[10];                                                    \
        *(float2*)(w+0)=S0; *(float2*)(w+2)=S1; *(float2*)(w+4)=S2;     \
        *(float2*)(w+6)=S3; *(float2*)(w+8)=S4;                         \
        const float2 fc = SF;                                           \
        LOADSLOT(S0,S1,S2,S3,S4,SF,CN)                                  \
        _Pragma("unroll")                                               \
        for (int dxi = 0; dxi < 9; ++dxi) {                             \
            acc[dxi].x += fc.x * w[dxi + 0];                            \
            acc[dxi].y += fc.y * w[dxi + 1];                            \
        }                                                               \
    }

// tail step: FMA only
#define STEPL(S0,S1,S2,S3,S4,SF)                                        \
    {                                                                   \
        float w[10];                                                    \
        *(float2*)(w+0)=S0; *(float2*)(w+2)=S1; *(float2*)(w+4)=S2;     \
        *(float2*)(w+6)=S3; *(float2*)(w+8)=S4;                         \
        const float2 fc = SF;                                           \
        _Pragma("unroll")                                               \
        for (int dxi = 0; dxi < 9; ++dxi) {                             \
            acc[dxi].x += fc.x * w[dxi + 0];                            \
            acc[dxi].y += fc.y * w[dxi + 1];                            \
        }                                                               \
    }

    // steady state: channels 0..123, loads run 4 ahead, no barriers anywhere
    #pragma unroll 1
    for (int cb = 0; cb < 124; cb += 4) {
        STEP(A0,A1,A2,A3,A4,AF, cb + 4)
        STEP(B0,B1,B2,B3,B4,BF, cb + 5)
        STEP(C0,C1,C2,C3,C4,CF, cb + 6)
        STEP(D0,D1,D2,D3,D4,DF, cb + 7)
    }
    // tail: channels 124..127 already in slots
    STEPL(A0,A1,A2,A3,A4,AF)
    STEPL(B0,B1,B2,B3,B4,BF)
    STEPL(C0,C1,C2,C3,C4,CF)
    STEPL(D0,D1,D2,D3,D4,DF)

    // epilogue: out[b, dyi*9 + dxi, y, X..X+1]
    const float scale = 1.0f / (float)C_;
    #pragma unroll
    for (int dxi = 0; dxi < 9; ++dxi) {
        const int d = dyi * 9 + dxi;
        float2 r = acc[dxi];
        r.x *= scale; r.y *= scale;
        *(float2*)(out + ((size_t)b * 81 + d) * HW_ + (size_t)y * W_ + X) = r;
    }
}

extern "C" void kernel_launch(void* const* d_in, const int* in_sizes, int n_in,
                              void* d_out, int out_size, void* d_ws, size_t ws_size,
                              hipStream_t stream) {
    const float* first  = (const float*)d_in[0];
    const float* second = (const float*)d_in[1];
    float* out = (float*)d_out;

    dim3 grid(W_ / TX, H_ / TY, B_ * 9);   // 3 x 32 x 36 = 3456 blocks
    dim3 block(128);
    corr_kernel<<<grid, block, 0, stream>>>(first, second, out);
}

// Round 2
// 299.898 us; speedup vs baseline: 1.5133x; 1.5133x over previous
//
#include <hip/hip_runtime.h>

// Correlation cost volume, MAX_DISP=4 (81 displacements).
// out[b,(dy+4)*9+(dx+4),y,x] = (1/C) * sum_c first[b,c,y,x]*second[b,c,y+dy,x+dx]
//
// R9: DX-SPLIT OCCUPANCY DOUBLING (merge-free). R7: latency-bound, 3456 waves
// = 3.375/SIMD, VALUBusy 25%, HBM 22%. R8 post-mortem: launch_bounds(128,6)
// capped VGPR at 85 < live set -> scratch spill (WRITE_SIZE 337MB = 10x output,
// VGPR 40, 3x slower). Lesson: raise waves WITHOUT shrinking the register
// budget below the live set.
// Fix: split each R7 block into two half-blocks by displacement column:
//   half=0 -> dxi 0..3 (dx -4..-1), window [X-4, X+4)
//   half=1 -> dxi 4..8 (dx  0..+4), window [X,   X+8)
// Each half needs only 2 window float4 (vs 3) + 1 first float4 per channel;
// outputs are DISJOINT planes -> no atomics/workspace. 3456 blocks x 2 waves
// = 6912 waves = 6.75/SIMD. Depth-2 pipeline (R4==R6: depth>2 buys nothing):
// live set ~= 24 slot + 20 acc + snapshot ~70 VGPR -> 7 waves/SIMD HW cap.
// launch_bounds(128,4) keeps a 128-VGPR budget (anti-spill insurance).
// T1 bijective XCD chunk-swizzle (3456%8==0): the 18 dy/half blocks sharing a
// first-tile + overlapping second rows land on one XCD's L2 (attacks the
// 176MB-vs-101MB-unique over-fetch). Zero barriers, zero LDS (R7-proven).

#define B_    4
#define C_    128
#define H_    128
#define W_    192
#define HW_   (H_ * W_)
#define CHW_  (C_ * HW_)

#define TX    64    // tile width (pixels) = 16 lanes * 4 px
#define TY    8     // tile height
#define NWG   3456  // 3 * 16 * 72
#define CPX   (NWG / 8)   // 432 blocks per XCD chunk

__global__ __launch_bounds__(128, 4)
void corr_kernel(const float* __restrict__ first,
                 const float* __restrict__ second,
                 float* __restrict__ out)
{
    // ---- T1 XCD swizzle: HW round-robins consecutive linear ids across the
    // 8 XCDs; remap so each XCD owns a contiguous 432-block chunk. A chunk
    // spans all x,y tiles and ~9 consecutive z slices -> first[b] tile and
    // second-row reuse stays in one XCD's L2. Bijective since NWG%8==0.
    const int lid = blockIdx.x + 3 * blockIdx.y + 48 * blockIdx.z;
    const int swz = (lid & 7) * CPX + (lid >> 3);
    const int z    = swz / 48;           // 0..71  (z = (b*9 + dyi)*2 + half)
    const int rem  = swz - 48 * z;
    const int y0i  = rem / 3;            // 0..15
    const int x0i  = rem - 3 * y0i;      // 0..2
    const int b    = z / 18;
    const int rr   = z - 18 * b;
    const int dyi  = rr >> 1;            // 0..8
    const int half = rr & 1;             // 0: dx -4..-1, 1: dx 0..+4

    const int t  = threadIdx.x;
    const int tx = t & 15;               // 0..15 (4 px each)
    const int ty = t >> 4;               // 0..7
    const int X  = x0i * TX + 4 * tx;    // first output x (mult of 4)
    const int y  = y0i * TY + ty;
    const int dy = dyi - 4;
    const int ys = y + dy;               // source row in second
    const int woff = 4 * half - 4;       // window base offset: -4 or 0

    const float* fptr = first  + (size_t)b * CHW_ + (size_t)y  * W_ + X;
    // window base: second[b, c, ys, X+woff] (guarded; only deref'd when valid)
    const float* wptr = second + (size_t)b * CHW_ + (size_t)ys * W_ + (X + woff);

    const bool rowv = (ys >= 0) && (ys < H_);
    // chunk0 = [X+woff, X+woff+4), chunk1 = [X+woff+4, X+woff+8)
    // each chunk is fully valid or fully in the zero-pad region:
    const bool v0 = rowv && (X + woff >= 0);        // only fails half=0, X=0
    const bool v1 = rowv && (X + woff + 8 <= W_);   // only fails half=1, X=188

    const float4 z4 = make_float4(0.f, 0.f, 0.f, 0.f);

    // depth-2 named pipeline slots: slot K holds channel cb+K's window + first
    float4 A0, A1, AF, B0, B1, BF;

#define LOADSLOT(S0, S1, SF, CN)                                        \
    {                                                                   \
        const size_t co = (size_t)(CN) * HW_;                           \
        S0 = v0 ? *(const float4*)(wptr + co)     : z4;                 \
        S1 = v1 ? *(const float4*)(wptr + co + 4) : z4;                 \
        SF = *(const float4*)(fptr + co);                               \
    }

    // prologue: channels 0,1
    LOADSLOT(A0, A1, AF, 0)
    LOADSLOT(B0, B1, BF, 1)

    // acc[j] = output plane dxi = 4*half + j. For half=0, acc[4] is computed
    // but discarded (uniform code path; 4 spare FMAs/step).
    float4 acc[5];
    #pragma unroll
    for (int i = 0; i < 5; ++i) acc[i] = z4;

// one step: snapshot slot (w[8] SROA'd to register renames), issue channel
// CN's loads into the slot (fly ~1.5 steps + TLP covers the rest), then FMA.
// out px X+p, plane j: second x = X + p + (4*half + j) - 4 = (X+woff)+(p+j)
// = w[p+j]  (p,j in 0..3 / j..4)
#define STEP(S0, S1, SF, CN)                                            \
    {                                                                   \
        float w[8];                                                     \
        *(float4*)(w + 0) = S0;                                         \
        *(float4*)(w + 4) = S1;                                         \
        const float4 fc = SF;                                           \
        LOADSLOT(S0, S1, SF, CN)                                        \
        _Pragma("unroll")                                               \
        for (int j = 0; j < 5; ++j) {                                   \
            acc[j].x += fc.x * w[j + 0];                                \
            acc[j].y += fc.y * w[j + 1];                                \
            acc[j].z += fc.z * w[j + 2];                                \
            acc[j].w += fc.w * w[j + 3];                                \
        }                                                               \
    }

#define STEPL(S0, S1, SF)                                               \
    {                                                                   \
        float w[8];                                                     \
        *(float4*)(w + 0) = S0;                                         \
        *(float4*)(w + 4) = S1;                                         \
        const float4 fc = SF;                                           \
        _Pragma("unroll")                                               \
        for (int j = 0; j < 5; ++j) {                                   \
            acc[j].x += fc.x * w[j + 0];                                \
            acc[j].y += fc.y * w[j + 1];                                \
            acc[j].z += fc.z * w[j + 2];                                \
            acc[j].w += fc.w * w[j + 3];                                \
        }                                                               \
    }

    // steady state: channels 0..125 consumed, loads run 2 ahead, no barriers
    #pragma unroll 1
    for (int cb = 0; cb < 126; cb += 2) {
        STEP(A0, A1, AF, cb + 2)
        STEP(B0, B1, BF, cb + 3)
    }
    // tail: channels 126,127 already in slots
    STEPL(A0, A1, AF)
    STEPL(B0, B1, BF)

    // epilogue: out[b, dyi*9 + 4*half + j, y, X..X+3]
    const float scale = 1.0f / (float)C_;
    const int dbase = dyi * 9 + 4 * half;
    float* obase = out + ((size_t)b * 81 + dbase) * HW_ + (size_t)y * W_ + X;
    #pragma unroll
    for (int j = 0; j < 4; ++j) {
        float4 rx = acc[j];
        rx.x *= scale; rx.y *= scale; rx.z *= scale; rx.w *= scale;
        *(float4*)(obase + (size_t)j * HW_) = rx;
    }
    if (half) {
        float4 rx = acc[4];
        rx.x *= scale; rx.y *= scale; rx.z *= scale; rx.w *= scale;
        *(float4*)(obase + (size_t)4 * HW_) = rx;
    }
}

extern "C" void kernel_launch(void* const* d_in, const int* in_sizes, int n_in,
                              void* d_out, int out_size, void* d_ws, size_t ws_size,
                              hipStream_t stream) {
    const float* first  = (const float*)d_in[0];
    const float* second = (const float*)d_in[1];
    float* out = (float*)d_out;

    dim3 grid(W_ / TX, H_ / TY, B_ * 9 * 2);   // 3 x 16 x 72 = 3456 blocks
    dim3 block(128);
    corr_kernel<<<grid, block, 0, stream>>>(first, second, out);
}

// Round 3
// 233.671 us; speedup vs baseline: 1.9422x; 1.2834x over previous
//
#include <hip/hip_runtime.h>

// Correlation cost volume, MAX_DISP=4 (81 displacements).
// out[b,(dy+4)*9+(dx+4),y,x] = (1/C) * sum_c first[b,c,y,x]*second[b,c,y+dy,x+dx]
//
// R10 = R9's dx-split, minus the two R9 mistakes.
// R9 post-mortem: (a) XCD chunk-swizzle DESTROYED locality the natural map
// already had -- 48 blocks/z-slice and 48%8==0 means HW round-robin puts all
// 72 z-slices of an xy-tile on ONE XCD (XCD=(x+3y)%8): the dy/half reuse group
// is co-located and co-timed for free. Swizzle gave 12.6MB/XCD working sets
// -> L2 thrash -> FETCH 176->630MB -> HBM latency on critical path -> 213us.
// (b) depth-2 pipeline: compiler collapsed it (VGPR 36 < live set), sinking
// loads to uses -> zero prefetch distance. Depth-4 held at VGPR 76 in R7.
// R10: dx-split (proven: occupancy 23->52%), NATURAL mapping, DEPTH-4.
//   half=0 -> dxi 0..3 (dx -4..-1), window [X-4, X+4)
//   half=1 -> dxi 4..8 (dx  0..+4), window [X,   X+8)
// Outputs disjoint -> no atomics. 3456 blocks x 2 waves = 6.75 waves/SIMD.
// Live set ~ 4 slots x 3 float4 + 5 float4 acc ~= 80 VGPR < 128 cap. Zero
// barriers, zero LDS (R7-proven).

#define B_    4
#define C_    128
#define H_    128
#define W_    192
#define HW_   (H_ * W_)
#define CHW_  (C_ * HW_)

#define TX    64    // tile width (pixels) = 16 lanes * 4 px
#define TY    8     // tile height

__global__ __launch_bounds__(128, 4)
void corr_kernel(const float* __restrict__ first,
                 const float* __restrict__ second,
                 float* __restrict__ out)
{
    const int t  = threadIdx.x;
    const int tx = t & 15;               // 0..15 (4 px each)
    const int ty = t >> 4;               // 0..7
    const int x0 = blockIdx.x * TX;
    const int y0 = blockIdx.y * TY;
    const int z  = blockIdx.z;           // (b*9 + dyi)*2 + half
    const int half = z & 1;              // 0: dx -4..-1, 1: dx 0..+4
    const int zz = z >> 1;               // b*9 + dyi
    const int b  = zz / 9;
    const int dyi = zz - 9 * b;          // 0..8
    const int dy  = dyi - 4;

    const int X  = x0 + 4 * tx;          // first output x (mult of 4)
    const int y  = y0 + ty;
    const int ys = y + dy;               // source row in second
    const int woff = 4 * half - 4;       // window base offset: -4 or 0

    const float* fptr = first  + (size_t)b * CHW_ + (size_t)y  * W_ + X;
    // window base: second[b, c, ys, X+woff] (guarded; only deref'd when valid)
    const float* wptr = second + (size_t)b * CHW_ + (size_t)ys * W_ + (X + woff);

    const bool rowv = (ys >= 0) && (ys < H_);
    // chunk0 = [X+woff, X+woff+4), chunk1 = [X+woff+4, X+woff+8)
    // each chunk is fully valid or fully in the zero-pad region:
    const bool v0 = rowv && (X + woff >= 0);        // only fails half=0, X=0
    const bool v1 = rowv && (X + woff + 8 <= W_);   // only fails half=1, X=188

    const float4 z4 = make_float4(0.f, 0.f, 0.f, 0.f);

    // depth-4 named pipeline slots: slot K holds channel cb+K's window + first
    float4 A0, A1, AF, B0, B1, BF, C0, C1, CF, D0, D1, DF;

#define LOADSLOT(S0, S1, SF, CN)                                        \
    {                                                                   \
        const size_t co = (size_t)(CN) * HW_;                           \
        S0 = v0 ? *(const float4*)(wptr + co)     : z4;                 \
        S1 = v1 ? *(const float4*)(wptr + co + 4) : z4;                 \
        SF = *(const float4*)(fptr + co);                               \
    }

    // prologue: channels 0..3
    LOADSLOT(A0, A1, AF, 0)
    LOADSLOT(B0, B1, BF, 1)
    LOADSLOT(C0, C1, CF, 2)
    LOADSLOT(D0, D1, DF, 3)

    // acc[j] = output plane dxi = 4*half + j. For half=0, acc[4] is computed
    // but discarded (uniform code path; 4 spare FMAs/step).
    float4 acc[5];
    #pragma unroll
    for (int i = 0; i < 5; ++i) acc[i] = z4;

// one step: snapshot slot (w[8] SROA'd to register renames), issue channel
// CN's loads into the slot (they fly ~3 more steps), then FMA.
// out px X+p, plane j: second x = X+p+(4*half+j)-4 = (X+woff)+(p+j) = w[p+j]
#define STEP(S0, S1, SF, CN)                                            \
    {                                                                   \
        float w[8];                                                     \
        *(float4*)(w + 0) = S0;                                         \
        *(float4*)(w + 4) = S1;                                         \
        const float4 fc = SF;                                           \
        LOADSLOT(S0, S1, SF, CN)                                        \
        _Pragma("unroll")                                               \
        for (int j = 0; j < 5; ++j) {                                   \
            acc[j].x += fc.x * w[j + 0];                                \
            acc[j].y += fc.y * w[j + 1];                                \
            acc[j].z += fc.z * w[j + 2];                                \
            acc[j].w += fc.w * w[j + 3];                                \
        }                                                               \
    }

#define STEPL(S0, S1, SF)                                               \
    {                                                                   \
        float w[8];                                                     \
        *(float4*)(w + 0) = S0;                                         \
        *(float4*)(w + 4) = S1;                                         \
        const float4 fc = SF;                                           \
        _Pragma("unroll")                                               \
        for (int j = 0; j < 5; ++j) {                                   \
            acc[j].x += fc.x * w[j + 0];                                \
            acc[j].y += fc.y * w[j + 1];                                \
            acc[j].z += fc.z * w[j + 2];                                \
            acc[j].w += fc.w * w[j + 3];                                \
        }                                                               \
    }

    // steady state: channels 0..123, loads run 4 ahead, no barriers anywhere
    #pragma unroll 1
    for (int cb = 0; cb < 124; cb += 4) {
        STEP(A0, A1, AF, cb + 4)
        STEP(B0, B1, BF, cb + 5)
        STEP(C0, C1, CF, cb + 6)
        STEP(D0, D1, DF, cb + 7)
    }
    // tail: channels 124..127 already in slots
    STEPL(A0, A1, AF)
    STEPL(B0, B1, BF)
    STEPL(C0, C1, CF)
    STEPL(D0, D1, DF)

    // epilogue: out[b, dyi*9 + 4*half + j, y, X..X+3]
    const float scale = 1.0f / (float)C_;
    const int dbase = dyi * 9 + 4 * half;
    float* obase = out + ((size_t)b * 81 + dbase) * HW_ + (size_t)y * W_ + X;
    #pragma unroll
    for (int j = 0; j < 4; ++j) {
        float4 rx = acc[j];
        rx.x *= scale; rx.y *= scale; rx.z *= scale; rx.w *= scale;
        *(float4*)(obase + (size_t)j * HW_) = rx;
    }
    if (half) {
        float4 rx = acc[4];
        rx.x *= scale; rx.y *= scale; rx.z *= scale; rx.w *= scale;
        *(float4*)(obase + (size_t)4 * HW_) = rx;
    }
}

extern "C" void kernel_launch(void* const* d_in, const int* in_sizes, int n_in,
                              void* d_out, int out_size, void* d_ws, size_t ws_size,
                              hipStream_t stream) {
    const float* first  = (const float*)d_in[0];
    const float* second = (const float*)d_in[1];
    float* out = (float*)d_out;

    dim3 grid(W_ / TX, H_ / TY, B_ * 9 * 2);   // 3 x 16 x 72 = 3456 blocks
    dim3 block(128);
    corr_kernel<<<grid, block, 0, stream>>>(first, second, out);
}